// Round 1
// baseline (439.561 us; speedup 1.0000x reference)
//
#include <hip/hip_runtime.h>

#define LSTR 264  // 256 + 8 shorts pad: A-frag b128 reads hit all 32 banks evenly

typedef short short4v __attribute__((ext_vector_type(4)));
typedef short short8v __attribute__((ext_vector_type(8)));
typedef float f32x4 __attribute__((ext_vector_type(4)));

__device__ __forceinline__ short f2bf(float f) {
  unsigned u = __float_as_uint(f);
  unsigned r = u + 0x7fffu + ((u >> 16) & 1u);  // round-to-nearest-even
  return (short)(r >> 16);
}

__device__ __forceinline__ short4v f2bf4(float4 v) {
  short4v s;
  s.x = f2bf(v.x); s.y = f2bf(v.y); s.z = f2bf(v.z); s.w = f2bf(v.w);
  return s;
}

// Weight prep: bf16 conversions + Wvo = Wo @ Wv, bvo = Wo @ bv + bo
__global__ __launch_bounds__(256) void prep_kernel(
    const float* __restrict__ Wq, const float* __restrict__ Wk,
    const float* __restrict__ Wv, const float* __restrict__ Wo,
    const float* __restrict__ bv, const float* __restrict__ bo,
    short* __restrict__ wq, short* __restrict__ wk, short* __restrict__ wv,
    short* __restrict__ wo, short* __restrict__ wvo, float* __restrict__ bvo) {
  __shared__ float srow[256];
  __shared__ float red[256];
  const int n = blockIdx.x, k = threadIdx.x;
  const int idx = n * 256 + k;
  const float wov = Wo[idx];
  srow[k] = wov;
  wq[idx] = f2bf(Wq[idx]);
  wk[idx] = f2bf(Wk[idx]);
  wv[idx] = f2bf(Wv[idx]);
  wo[idx] = f2bf(wov);
  red[k] = wov * bv[k];
  __syncthreads();
  float acc = 0.f;
#pragma unroll 8
  for (int j = 0; j < 256; ++j) acc += srow[j] * Wv[j * 256 + k];
  wvo[idx] = f2bf(acc);
  for (int s = 128; s > 0; s >>= 1) {
    if (k < s) red[k] += red[k + s];
    __syncthreads();
  }
  if (k == 0) bvo[n] = red[0] + bo[n];
}

// One K=256 GEMM pass for a wave: 2 m-subtiles (16 rows each) x 4 n-tiles (16 cols each)
// A from LDS (bf16 rows, stride LSTR), B = W[n][k] row-major bf16 from global (L2-resident)
__device__ __forceinline__ void gemm_pass(const short* A, const short* __restrict__ W,
                                          int nbase, int col, int quad, f32x4 acc[2][4]) {
  const short* a0p = A + col * LSTR + quad * 8;
  const short* a1p = a0p + 16 * LSTR;
  const short* wp = W + (nbase + col) * 256 + quad * 8;
#pragma unroll
  for (int ks = 0; ks < 8; ++ks) {
    short8v a0 = *(const short8v*)(a0p + ks * 32);
    short8v a1 = *(const short8v*)(a1p + ks * 32);
#pragma unroll
    for (int nt = 0; nt < 4; ++nt) {
      short8v b = *(const short8v*)(wp + nt * 4096 + ks * 32);
      acc[0][nt] = __builtin_amdgcn_mfma_f32_16x16x32_bf16(a0, b, acc[0][nt], 0, 0, 0);
      acc[1][nt] = __builtin_amdgcn_mfma_f32_16x16x32_bf16(a1, b, acc[1][nt], 0, 0, 0);
    }
  }
}

__global__ __launch_bounds__(256, 3) void fused_kernel(
    const float* __restrict__ pred, const float* __restrict__ cemb,
    const short* __restrict__ wq, const short* __restrict__ wk,
    const short* __restrict__ wv, const short* __restrict__ wo,
    const short* __restrict__ wvo, const float* __restrict__ bq,
    const float* __restrict__ bvo, float* __restrict__ out) {
  __shared__ __align__(16) short bufP[32 * LSTR];   // p tile, later gdV tile
  __shared__ __align__(16) short bufD[32 * LSTR];   // c0-c1 tile
  __shared__ __align__(16) short bufC1[32 * LSTR];  // c1 tile
  const int tid = threadIdx.x;
  const size_t t0 = (size_t)blockIdx.x * 32;

  // Stage: p -> bufP, (c0-c1) -> bufD, c1 -> bufC1 (fp32->bf16)
  {
    const int r = tid >> 3;
    const int c0 = tid & 7;
    const float4* prow = (const float4*)(pred + (t0 + r) * 256);
    const float4* crow = (const float4*)(cemb + (t0 + r) * 512);
    short* pd = bufP + r * LSTR;
    short* dd = bufD + r * LSTR;
    short* cd = bufC1 + r * LSTR;
#pragma unroll
    for (int i = 0; i < 8; ++i) {
      const int j = c0 + 8 * i;
      float4 v = prow[j];
      *(short4v*)(pd + 4 * j) = f2bf4(v);
      float4 a = crow[j];
      float4 b = crow[64 + j];
      float4 d4 = make_float4(a.x - b.x, a.y - b.y, a.z - b.z, a.w - b.w);
      *(short4v*)(dd + 4 * j) = f2bf4(d4);
      *(short4v*)(cd + 4 * j) = f2bf4(b);
    }
  }
  __syncthreads();

  const int lane = tid & 63;
  const int w = tid >> 6;      // wave = head
  const int col = lane & 15;
  const int quad = lane >> 4;
  const int nbase = w * 64;

  f32x4 accQ[2][4] = {};
  gemm_pass(bufP, wq, nbase, col, quad, accQ);
  f32x4 accK[2][4] = {};
  gemm_pass(bufD, wk, nbase, col, quad, accK);

  float bqv[4];
#pragma unroll
  for (int nt = 0; nt < 4; ++nt) bqv[nt] = bq[nbase + nt * 16 + col];

  // z[m][head] = (Q+bq) . dK over this head's 64 cols; reduce across 16 lanes of quad
  float g[2][4];
#pragma unroll
  for (int ms = 0; ms < 2; ++ms) {
#pragma unroll
    for (int r = 0; r < 4; ++r) {
      float zz = 0.f;
#pragma unroll
      for (int nt = 0; nt < 4; ++nt)
        zz += (accQ[ms][nt][r] + bqv[nt]) * accK[ms][nt][r];
      zz += __shfl_xor(zz, 1);
      zz += __shfl_xor(zz, 2);
      zz += __shfl_xor(zz, 4);
      zz += __shfl_xor(zz, 8);
      g[ms][r] = 1.f / (1.f + __expf(-0.125f * zz));  // sigmoid(z/sqrt(64))
    }
  }

  f32x4 accV[2][4] = {};
  gemm_pass(bufD, wv, nbase, col, quad, accV);

  __syncthreads();  // all waves done reading bufP (Q gemm)
  // gdV -> bufP as bf16 A-tile (C/D layout: row = quad*4+reg, col = nt*16+col)
#pragma unroll
  for (int ms = 0; ms < 2; ++ms)
#pragma unroll
    for (int nt = 0; nt < 4; ++nt)
#pragma unroll
      for (int r = 0; r < 4; ++r)
        bufP[(ms * 16 + quad * 4 + r) * LSTR + nbase + nt * 16 + col] =
            f2bf(g[ms][r] * accV[ms][nt][r]);
  __syncthreads();

  // out = c1 @ Wvo^T + gdV @ Wo^T + bvo
  f32x4 accO[2][4] = {};
  gemm_pass(bufC1, wvo, nbase, col, quad, accO);
  gemm_pass(bufP, wo, nbase, col, quad, accO);

  float bov[4];
#pragma unroll
  for (int nt = 0; nt < 4; ++nt) bov[nt] = bvo[nbase + nt * 16 + col];

#pragma unroll
  for (int ms = 0; ms < 2; ++ms)
#pragma unroll
    for (int nt = 0; nt < 4; ++nt)
#pragma unroll
      for (int r = 0; r < 4; ++r)
        out[(t0 + ms * 16 + quad * 4 + r) * 256 + nbase + nt * 16 + col] =
            accO[ms][nt][r] + bov[nt];
}

extern "C" void kernel_launch(void* const* d_in, const int* in_sizes, int n_in,
                              void* d_out, int out_size, void* d_ws, size_t ws_size,
                              hipStream_t stream) {
  const float* pred = (const float*)d_in[0];
  const float* cemb = (const float*)d_in[1];
  const float* Wq = (const float*)d_in[2];
  const float* bq = (const float*)d_in[3];
  const float* Wk = (const float*)d_in[4];
  (void)Wk;  // used below; bk (d_in[5]) cancels in K0-K1
  const float* Wv = (const float*)d_in[6];
  const float* bv = (const float*)d_in[7];
  const float* Wo = (const float*)d_in[8];
  const float* bo = (const float*)d_in[9];
  float* out = (float*)d_out;

  short* wq = (short*)d_ws;
  short* wk = wq + 65536;
  short* wv = wk + 65536;
  short* wo = wv + 65536;
  short* wvo = wo + 65536;
  float* bvo = (float*)(wvo + 65536);  // total ws use: 656,384 bytes

  prep_kernel<<<256, 256, 0, stream>>>(Wq, (const float*)d_in[4], Wv, Wo, bv, bo,
                                       wq, wk, wv, wo, wvo, bvo);
  fused_kernel<<<2048, 256, 0, stream>>>(pred, cemb, wq, wk, wv, wo, wvo, bq, bvo, out);
}

// Round 2
// 428.594 us; speedup vs baseline: 1.0256x; 1.0256x over previous
//
#include <hip/hip_runtime.h>

#define LSTR 264  // 256 + 8 shorts pad: 528B rows keep 16B alignment, even bank spread

typedef short short4v __attribute__((ext_vector_type(4)));
typedef short short8v __attribute__((ext_vector_type(8)));
typedef float f32x4 __attribute__((ext_vector_type(4)));

#define MFMA(a, b, c) __builtin_amdgcn_mfma_f32_16x16x32_bf16((a), (b), (c), 0, 0, 0)

__device__ __forceinline__ short f2bf(float f) {
  unsigned u = __float_as_uint(f);
  unsigned r = u + 0x7fffu + ((u >> 16) & 1u);  // round-to-nearest-even
  return (short)(r >> 16);
}

__device__ __forceinline__ short4v f2bf4(float4 v) {
  short4v s;
  s.x = f2bf(v.x); s.y = f2bf(v.y); s.z = f2bf(v.z); s.w = f2bf(v.w);
  return s;
}

// Weight prep: bf16 conversions + Wvo = Wo @ Wv, bvo = Wo @ bv + bo
__global__ __launch_bounds__(256) void prep_kernel(
    const float* __restrict__ Wq, const float* __restrict__ Wk,
    const float* __restrict__ Wv, const float* __restrict__ Wo,
    const float* __restrict__ bv, const float* __restrict__ bo,
    short* __restrict__ wq, short* __restrict__ wk, short* __restrict__ wv,
    short* __restrict__ wo, short* __restrict__ wvo, float* __restrict__ bvo) {
  __shared__ float srow[256];
  __shared__ float red[256];
  const int n = blockIdx.x, k = threadIdx.x;
  const int idx = n * 256 + k;
  const float wov = Wo[idx];
  srow[k] = wov;
  wq[idx] = f2bf(Wq[idx]);
  wk[idx] = f2bf(Wk[idx]);
  wv[idx] = f2bf(Wv[idx]);
  wo[idx] = f2bf(wov);
  red[k] = wov * bv[k];
  __syncthreads();
  float acc = 0.f;
#pragma unroll 16
  for (int j = 0; j < 256; ++j) acc += srow[j] * Wv[j * 256 + k];
  wvo[idx] = f2bf(acc);
  for (int s = 128; s > 0; s >>= 1) {
    if (k < s) red[k] += red[k + s];
    __syncthreads();
  }
  if (k == 0) bvo[n] = red[0] + bo[n];
}

// One K=256 GEMM pass, software-pipelined: next-ks A (ds_read_b128) and B
// (global dwordx4, L2-resident weights) are issued BEFORE the current ks's
// 8 MFMAs, with rotating registers. All offsets are compile-time immediates.
__device__ __forceinline__ void gemm1(const short* A, const short* __restrict__ W,
                                      int nbase, int col, int quad, f32x4 acc[2][4]) {
  const short* a0p = A + col * LSTR + quad * 8;
  const short* a1p = a0p + 16 * LSTR;
  const short* wp = W + (nbase + col) * 256 + quad * 8;
  short8v a0c = *(const short8v*)a0p;
  short8v a1c = *(const short8v*)a1p;
  short8v bc0 = *(const short8v*)(wp + 4096 * 0);
  short8v bc1 = *(const short8v*)(wp + 4096 * 1);
  short8v bc2 = *(const short8v*)(wp + 4096 * 2);
  short8v bc3 = *(const short8v*)(wp + 4096 * 3);
#pragma unroll
  for (int ks = 0; ks < 8; ++ks) {
    const int kn = (ks + 1) & 7;  // wrap avoids UB; extra tail loads are free
    short8v a0n = *(const short8v*)(a0p + kn * 32);
    short8v a1n = *(const short8v*)(a1p + kn * 32);
    short8v bn0 = *(const short8v*)(wp + 4096 * 0 + kn * 32);
    short8v bn1 = *(const short8v*)(wp + 4096 * 1 + kn * 32);
    short8v bn2 = *(const short8v*)(wp + 4096 * 2 + kn * 32);
    short8v bn3 = *(const short8v*)(wp + 4096 * 3 + kn * 32);
    acc[0][0] = MFMA(a0c, bc0, acc[0][0]);
    acc[1][0] = MFMA(a1c, bc0, acc[1][0]);
    acc[0][1] = MFMA(a0c, bc1, acc[0][1]);
    acc[1][1] = MFMA(a1c, bc1, acc[1][1]);
    acc[0][2] = MFMA(a0c, bc2, acc[0][2]);
    acc[1][2] = MFMA(a1c, bc2, acc[1][2]);
    acc[0][3] = MFMA(a0c, bc3, acc[0][3]);
    acc[1][3] = MFMA(a1c, bc3, acc[1][3]);
    a0c = a0n; a1c = a1n;
    bc0 = bn0; bc1 = bn1; bc2 = bn2; bc3 = bn3;
  }
}

__global__ __launch_bounds__(256, 3) void fused_kernel(
    const float* __restrict__ pred, const float* __restrict__ cemb,
    const short* __restrict__ wq, const short* __restrict__ wk,
    const short* __restrict__ wv, const short* __restrict__ wo,
    const short* __restrict__ wvo, const float* __restrict__ bq,
    const float* __restrict__ bvo, float* __restrict__ out) {
  __shared__ __align__(16) short bufP[32 * LSTR];   // p tile, later gdV tile
  __shared__ __align__(16) short bufD[32 * LSTR];   // c0-c1 tile
  __shared__ __align__(16) short bufC1[32 * LSTR];  // c1 tile
  const int tid = threadIdx.x;
  const size_t t0 = (size_t)blockIdx.x * 32;

  // Stage: all 24 float4 HBM loads per thread issued up-front into registers
  // (full MLP), then convert fp32->bf16 and write LDS.
  {
    const int r = tid >> 3;
    const int c0 = tid & 7;
    const float4* prow = (const float4*)(pred + (t0 + r) * 256);
    const float4* crow = (const float4*)(cemb + (t0 + r) * 512);
    float4 pv[8], av[8], bw[8];
#pragma unroll
    for (int i = 0; i < 8; ++i) pv[i] = prow[c0 + 8 * i];
#pragma unroll
    for (int i = 0; i < 8; ++i) av[i] = crow[c0 + 8 * i];
#pragma unroll
    for (int i = 0; i < 8; ++i) bw[i] = crow[64 + c0 + 8 * i];
    short* pd = bufP + r * LSTR;
    short* dd = bufD + r * LSTR;
    short* cd = bufC1 + r * LSTR;
#pragma unroll
    for (int i = 0; i < 8; ++i) {
      const int j = c0 + 8 * i;
      *(short4v*)(pd + 4 * j) = f2bf4(pv[i]);
      float4 d4 = make_float4(av[i].x - bw[i].x, av[i].y - bw[i].y,
                              av[i].z - bw[i].z, av[i].w - bw[i].w);
      *(short4v*)(dd + 4 * j) = f2bf4(d4);
      *(short4v*)(cd + 4 * j) = f2bf4(bw[i]);
    }
  }
  __syncthreads();

  const int lane = tid & 63;
  const int w = tid >> 6;      // wave = head
  const int col = lane & 15;
  const int quad = lane >> 4;
  const int nbase = w * 64;

  float bqv[4];
#pragma unroll
  for (int nt = 0; nt < 4; ++nt) bqv[nt] = bq[nbase + nt * 16 + col];

  f32x4 accQ[2][4] = {};
  gemm1(bufP, wq, nbase, col, quad, accQ);
  f32x4 accK[2][4] = {};
  gemm1(bufD, wk, nbase, col, quad, accK);

  // z[m][head] = (Q+bq) . dK over this head's 64 cols; reduce across the
  // 16 lanes of each quad-row; g = sigmoid(z/sqrt(D))
  float g[2][4];
#pragma unroll
  for (int ms = 0; ms < 2; ++ms) {
#pragma unroll
    for (int r = 0; r < 4; ++r) {
      float zz = 0.f;
#pragma unroll
      for (int nt = 0; nt < 4; ++nt)
        zz += (accQ[ms][nt][r] + bqv[nt]) * accK[ms][nt][r];
      zz += __shfl_xor(zz, 1);
      zz += __shfl_xor(zz, 2);
      zz += __shfl_xor(zz, 4);
      zz += __shfl_xor(zz, 8);
      g[ms][r] = 1.f / (1.f + __expf(-0.125f * zz));
    }
  }

  f32x4 accV[2][4] = {};
  gemm1(bufD, wv, nbase, col, quad, accV);

  __syncthreads();  // all waves done reading bufP (Q gemm)
  // gdV -> bufP as bf16 A-tile (C/D layout: row = quad*4+reg, col = nt*16+col)
#pragma unroll
  for (int ms = 0; ms < 2; ++ms)
#pragma unroll
    for (int nt = 0; nt < 4; ++nt)
#pragma unroll
      for (int r = 0; r < 4; ++r)
        bufP[(ms * 16 + quad * 4 + r) * LSTR + nbase + nt * 16 + col] =
            f2bf(g[ms][r] * accV[ms][nt][r]);
  __syncthreads();

  // out = c1 @ Wvo^T + gdV @ Wo^T + bvo
  f32x4 accO[2][4] = {};
  gemm1(bufC1, wvo, nbase, col, quad, accO);
  gemm1(bufP, wo, nbase, col, quad, accO);

  float bov[4];
#pragma unroll
  for (int nt = 0; nt < 4; ++nt) bov[nt] = bvo[nbase + nt * 16 + col];

#pragma unroll
  for (int ms = 0; ms < 2; ++ms)
#pragma unroll
    for (int nt = 0; nt < 4; ++nt)
#pragma unroll
      for (int r = 0; r < 4; ++r)
        out[(t0 + ms * 16 + quad * 4 + r) * 256 + nbase + nt * 16 + col] =
            accO[ms][nt][r] + bov[nt];
}

extern "C" void kernel_launch(void* const* d_in, const int* in_sizes, int n_in,
                              void* d_out, int out_size, void* d_ws, size_t ws_size,
                              hipStream_t stream) {
  const float* pred = (const float*)d_in[0];
  const float* cemb = (const float*)d_in[1];
  const float* Wq = (const float*)d_in[2];
  const float* bq = (const float*)d_in[3];
  const float* Wk = (const float*)d_in[4];
  const float* Wv = (const float*)d_in[6];
  const float* bv = (const float*)d_in[7];
  const float* Wo = (const float*)d_in[8];
  const float* bo = (const float*)d_in[9];
  float* out = (float*)d_out;

  short* wq = (short*)d_ws;
  short* wk = wq + 65536;
  short* wv = wk + 65536;
  short* wo = wv + 65536;
  short* wvo = wo + 65536;
  float* bvo = (float*)(wvo + 65536);  // total ws use: 656,384 bytes

  prep_kernel<<<256, 256, 0, stream>>>(Wq, Wk, Wv, Wo, bv, bo,
                                       wq, wk, wv, wo, wvo, bvo);
  fused_kernel<<<2048, 256, 0, stream>>>(pred, cemb, wq, wk, wv, wo, wvo, bq, bvo, out);
}

// Round 4
// 336.618 us; speedup vs baseline: 1.3058x; 1.2732x over previous
//
#include <hip/hip_runtime.h>

#define LSTR 264  // 256 + 8 shorts pad: 528B rows keep 16B alignment for ds_read_b128

typedef short short4v __attribute__((ext_vector_type(4)));
typedef short short8v __attribute__((ext_vector_type(8)));
typedef float f32x4 __attribute__((ext_vector_type(4)));

#define MFMA(a, b, c) __builtin_amdgcn_mfma_f32_16x16x32_bf16((a), (b), (c), 0, 0, 0)

__device__ __forceinline__ short f2bf(float f) {
  unsigned u = __float_as_uint(f);
  unsigned r = u + 0x7fffu + ((u >> 16) & 1u);  // round-to-nearest-even
  return (short)(r >> 16);
}

__device__ __forceinline__ short4v f2bf4(float4 v) {
  short4v s;
  s.x = f2bf(v.x); s.y = f2bf(v.y); s.z = f2bf(v.z); s.w = f2bf(v.w);
  return s;
}

// Packed-fragment index: matrix row n = h*64 + nt*16 + col, k = ks*32 + quad*8 + j
// -> packed[h*16384 + (ks*4+nt)*512 + (quad*16+col)*8 + j]
// A wave's B-fragment load is then ONE contiguous 1KB global_load_dwordx4.

// prep1: wvo = Wo @ Wv (written directly in packed bf16), bvo = Wo@bv + bo
__global__ __launch_bounds__(256) void prep1_kernel(
    const float* __restrict__ Wv, const float* __restrict__ Wo,
    const float* __restrict__ bv, const float* __restrict__ bo,
    short* __restrict__ pvo, float* __restrict__ bvo) {
  __shared__ float srow[256];
  __shared__ float red[256];
  const int n = blockIdx.x, k = threadIdx.x;
  const float wov = Wo[n * 256 + k];
  srow[k] = wov;
  red[k] = wov * bv[k];
  __syncthreads();
  float acc = 0.f;
#pragma unroll 16
  for (int j = 0; j < 256; ++j) acc += srow[j] * Wv[j * 256 + k];
  // packed store of wvo[n][k]
  const int h = n >> 6, nt = (n >> 4) & 3, col = n & 15;
  const int ks = k >> 5, quad = (k >> 3) & 3, j8 = k & 7;
  pvo[h * 16384 + (ks * 4 + nt) * 512 + (quad * 16 + col) * 8 + j8] = f2bf(acc);
  for (int s = 128; s > 0; s >>= 1) {
    if (k < s) red[k] += red[k + s];
    __syncthreads();
  }
  if (k == 0) bvo[n] = red[0] + bo[n];
}

// prep2: pack Wq/Wk/Wv/Wo into fragment order (bf16). 8192 threads, 16B per store.
__global__ __launch_bounds__(256) void pack_kernel(
    const float* __restrict__ Wq, const float* __restrict__ Wk,
    const float* __restrict__ Wv, const float* __restrict__ Wo,
    short* __restrict__ pq, short* __restrict__ pk,
    short* __restrict__ pv, short* __restrict__ po) {
  const int g = blockIdx.x * 256 + threadIdx.x;  // 0..8191
  const int n = g >> 5;
  const int c8 = g & 31;
  const int h = n >> 6, nt = (n >> 4) & 3, col = n & 15;
  const int ks = c8 >> 2, quad = c8 & 3;
  const int src = n * 256 + c8 * 8;
  const int dst = h * 16384 + (ks * 4 + nt) * 512 + (quad * 16 + col) * 8;
  const float4* q4 = (const float4*)(Wq + src);
  const float4* k4 = (const float4*)(Wk + src);
  const float4* v4 = (const float4*)(Wv + src);
  const float4* o4 = (const float4*)(Wo + src);
  float4 qa = q4[0], qb = q4[1], ka = k4[0], kb = k4[1];
  float4 va = v4[0], vb = v4[1], oa = o4[0], ob = o4[1];
  *(short4v*)(pq + dst) = f2bf4(qa); *(short4v*)(pq + dst + 4) = f2bf4(qb);
  *(short4v*)(pk + dst) = f2bf4(ka); *(short4v*)(pk + dst + 4) = f2bf4(kb);
  *(short4v*)(pv + dst) = f2bf4(va); *(short4v*)(pv + dst + 4) = f2bf4(vb);
  *(short4v*)(po + dst) = f2bf4(oa); *(short4v*)(po + dst + 4) = f2bf4(ob);
}

// One K=256 GEMM pass. A from LDS (ds_read_b128, depth-1 rotate); B from the
// packed weight array: fragment f = ks*4+nt is ONE coalesced 1KB wave-load at
// wb + f*512 shorts, prefetched depth-2 with rotating registers.
__device__ __forceinline__ void gemm1(const short* A, const short* __restrict__ wb,
                                      int col, int quad, f32x4 acc[2][4]) {
  const short* a0p = A + col * LSTR + quad * 8;
  const short* a1p = a0p + 16 * LSTR;
  short8v a0c = *(const short8v*)a0p;
  short8v a1c = *(const short8v*)a1p;
  short8v b0 = *(const short8v*)(wb);
  short8v b1 = *(const short8v*)(wb + 512);
#pragma unroll
  for (int ks = 0; ks < 8; ++ks) {
    const int kn = (ks + 1) & 7;  // wrap avoids OOB; tail reloads are free
    short8v a0n = *(const short8v*)(a0p + kn * 32);
    short8v a1n = *(const short8v*)(a1p + kn * 32);
#pragma unroll
    for (int nt = 0; nt < 4; ++nt) {
      const int f = ks * 4 + nt;
      short8v bn = *(const short8v*)(wb + ((f + 2) & 31) * 512);
      acc[0][nt] = MFMA(a0c, b0, acc[0][nt]);
      acc[1][nt] = MFMA(a1c, b0, acc[1][nt]);
      b0 = b1; b1 = bn;
    }
    a0c = a0n; a1c = a1n;
  }
}

__global__ __launch_bounds__(256, 3) void fused_kernel(
    const float* __restrict__ pred, const float* __restrict__ cemb,
    const short* __restrict__ pq, const short* __restrict__ pk,
    const short* __restrict__ pv, const short* __restrict__ po,
    const short* __restrict__ pvo, const float* __restrict__ bq,
    const float* __restrict__ bvo, float* __restrict__ out) {
  __shared__ __align__(16) short bufP[32 * LSTR];   // p tile, later gdV tile
  __shared__ __align__(16) short bufD[32 * LSTR];   // c0-c1 tile
  __shared__ __align__(16) short bufC1[32 * LSTR];  // c1 tile
  const int tid = threadIdx.x;
  const size_t t0 = (size_t)blockIdx.x * 32;

  // Stage: all 24 float4 HBM loads per thread issued up-front into registers,
  // then convert fp32->bf16 and write LDS.
  {
    const int r = tid >> 3;
    const int c0 = tid & 7;
    const float4* prow = (const float4*)(pred + (t0 + r) * 256);
    const float4* crow = (const float4*)(cemb + (t0 + r) * 512);
    float4 pv_[8], av[8], bw[8];
#pragma unroll
    for (int i = 0; i < 8; ++i) pv_[i] = prow[c0 + 8 * i];
#pragma unroll
    for (int i = 0; i < 8; ++i) av[i] = crow[c0 + 8 * i];
#pragma unroll
    for (int i = 0; i < 8; ++i) bw[i] = crow[64 + c0 + 8 * i];
    short* pd = bufP + r * LSTR;
    short* dd = bufD + r * LSTR;
    short* cd = bufC1 + r * LSTR;
#pragma unroll
    for (int i = 0; i < 8; ++i) {
      const int j = c0 + 8 * i;
      *(short4v*)(pd + 4 * j) = f2bf4(pv_[i]);
      float4 d4 = make_float4(av[i].x - bw[i].x, av[i].y - bw[i].y,
                              av[i].z - bw[i].z, av[i].w - bw[i].w);
      *(short4v*)(dd + 4 * j) = f2bf4(d4);
      *(short4v*)(cd + 4 * j) = f2bf4(bw[i]);
    }
  }
  __syncthreads();

  const int lane = tid & 63;
  const int w = tid >> 6;      // wave = head
  const int col = lane & 15;
  const int quad = lane >> 4;
  const int nbase = w * 64;
  const int woff = w * 16384 + lane * 8;  // packed-weight base for this wave

  float bqv[4];
#pragma unroll
  for (int nt = 0; nt < 4; ++nt) bqv[nt] = bq[nbase + nt * 16 + col];

  f32x4 accQ[2][4] = {};
  gemm1(bufP, pq + woff, col, quad, accQ);
  f32x4 accK[2][4] = {};
  gemm1(bufD, pk + woff, col, quad, accK);

  // z[m][head] = (Q+bq) . dK over this head's 64 cols; reduce across the
  // 16 lanes of each quad-row; g = sigmoid(z/sqrt(D))
  float g[2][4];
#pragma unroll
  for (int ms = 0; ms < 2; ++ms) {
#pragma unroll
    for (int r = 0; r < 4; ++r) {
      float zz = 0.f;
#pragma unroll
      for (int nt = 0; nt < 4; ++nt)
        zz += (accQ[ms][nt][r] + bqv[nt]) * accK[ms][nt][r];
      zz += __shfl_xor(zz, 1);
      zz += __shfl_xor(zz, 2);
      zz += __shfl_xor(zz, 4);
      zz += __shfl_xor(zz, 8);
      g[ms][r] = 1.f / (1.f + __expf(-0.125f * zz));
    }
  }

  f32x4 accV[2][4] = {};
  gemm1(bufD, pv + woff, col, quad, accV);

  __syncthreads();  // all waves done reading bufP (Q gemm)
  // gdV -> bufP as bf16 A-tile (C/D layout: row = quad*4+reg, col = nt*16+col)
#pragma unroll
  for (int ms = 0; ms < 2; ++ms)
#pragma unroll
    for (int nt = 0; nt < 4; ++nt)
#pragma unroll
      for (int r = 0; r < 4; ++r)
        bufP[(ms * 16 + quad * 4 + r) * LSTR + nbase + nt * 16 + col] =
            f2bf(g[ms][r] * accV[ms][nt][r]);
  __syncthreads();

  // out = c1 @ Wvo^T + gdV @ Wo^T + bvo
  f32x4 accO[2][4] = {};
  gemm1(bufC1, pvo + woff, col, quad, accO);
  gemm1(bufP, po + woff, col, quad, accO);

  float bov[4];
#pragma unroll
  for (int nt = 0; nt < 4; ++nt) bov[nt] = bvo[nbase + nt * 16 + col];

#pragma unroll
  for (int ms = 0; ms < 2; ++ms)
#pragma unroll
    for (int nt = 0; nt < 4; ++nt)
#pragma unroll
      for (int r = 0; r < 4; ++r)
        out[(t0 + ms * 16 + quad * 4 + r) * 256 + nbase + nt * 16 + col] =
            accO[ms][nt][r] + bov[nt];
}

extern "C" void kernel_launch(void* const* d_in, const int* in_sizes, int n_in,
                              void* d_out, int out_size, void* d_ws, size_t ws_size,
                              hipStream_t stream) {
  const float* pred = (const float*)d_in[0];
  const float* cemb = (const float*)d_in[1];
  const float* Wq = (const float*)d_in[2];
  const float* bq = (const float*)d_in[3];
  const float* Wk = (const float*)d_in[4];
  const float* Wv = (const float*)d_in[6];
  const float* bv = (const float*)d_in[7];
  const float* Wo = (const float*)d_in[8];
  const float* bo = (const float*)d_in[9];
  float* out = (float*)d_out;

  short* pq = (short*)d_ws;
  short* pk = pq + 65536;
  short* pv = pk + 65536;
  short* po = pv + 65536;
  short* pvo = po + 65536;
  float* bvo = (float*)(pvo + 65536);  // total ws use: 656,384 bytes

  prep1_kernel<<<256, 256, 0, stream>>>(Wv, Wo, bv, bo, pvo, bvo);
  pack_kernel<<<32, 256, 0, stream>>>(Wq, Wk, Wv, Wo, pq, pk, pv, po);
  fused_kernel<<<2048, 256, 0, stream>>>(pred, cemb, pq, pk, pv, po, pvo, bq, bvo, out);
}